// Round 12
// baseline (142.305 us; speedup 1.0000x reference)
//
#include <hip/hip_runtime.h>
#include <hip/hip_bf16.h>
#include <math.h>

#define BB 64
#define DD 256
#define TT 24
#define NR 289

typedef float f32x4  __attribute__((ext_vector_type(4)));
typedef float f32x16 __attribute__((ext_vector_type(16)));
typedef short bf16x8 __attribute__((ext_vector_type(8)));

// ws layout (bytes) — ALL operands fragment-major (lane-minor, 16B/lane):
#define ETF_OFF  0ul                     // eTf  [64][32 sidx][32 r] bf16x8     1,048,576
#define VTF_OFF  1048576ul               // vTf  [64][10 nt][32 sidx][32 r]    10,485,760
#define VB2_OFF  11534336ul              // vbf2 [64][8 dt][40 ks][32 r]       10,485,760
#define EE_OFF   22020096ul              // eE   [64][8 dt][2 g2][12 reg][32 r] f32 1,572,864
#define SMAT_OFF 23592960ul              // Smat [4096] f32

// ---- e -> eTf fragments (GEMM1 A) + eE f32 fragments (epilogue)
__global__ void conv_e_kernel(const float* __restrict__ e,
                              __hip_bfloat16* __restrict__ eTf,
                              float* __restrict__ eE) {
    int i = blockIdx.x, tid = threadIdx.x;
    const float* ei = e + (size_t)i * DD * TT;
    bf16x8* dst = (bf16x8*)eTf + (size_t)i * 1024;
    #pragma unroll
    for (int p = 0; p < 4; ++p) {
        int idx = tid + p * 256;
        int r = idx & 31, sidx = idx >> 5;
        int d0 = sidx * 8;
        __hip_bfloat16 tmp[8];
        #pragma unroll
        for (int q = 0; q < 8; ++q) {
            float f = (r < TT) ? ei[(d0 + q) * TT + r] : 0.f;
            tmp[q] = __float2bfloat16(f);
        }
        dst[idx] = *(bf16x8*)tmp;
    }
    float* dstE = eE + (size_t)i * 6144;
    #pragma unroll
    for (int p = 0; p < 24; ++p) {
        int idx = tid + p * 256;
        int r = idx & 31, rest = idx >> 5;
        int reg = rest % 12, gdt = rest / 12;
        int g2 = gdt & 1, dt = gdt >> 1;
        int t = (reg & 3) + 8 * (reg >> 2) + 4 * g2;
        dstE[idx] = ei[(dt * 32 + r) * TT + t];
    }
}

// ---- v -> vTf (GEMM1 B, transposed) + vbf2 (GEMM2 B), both fragment-major
__global__ __launch_bounds__(256) void conv_v_kernel(const float* __restrict__ v,
                                                     __hip_bfloat16* __restrict__ vTf,
                                                     __hip_bfloat16* __restrict__ vbf2) {
    __shared__ float ld[32][321];
    int j = blockIdx.x >> 3;
    int dbase = (blockIdx.x & 7) * 32;
    int tid = threadIdx.x;
    const float* vj = v + (size_t)j * DD * NR;
    for (int r = 0; r < 32; ++r) {
        const float* row = vj + (size_t)(dbase + r) * NR;
        ld[r][tid] = row[tid];
        if (tid < 64) {
            int n = 256 + tid;
            ld[r][n] = (n < NR) ? row[n] : 0.f;
        }
    }
    __syncthreads();
    {
        bf16x8* dT = (bf16x8*)vTf + (size_t)j * 10240;
        #pragma unroll
        for (int p = 0; p < 5; ++p) {
            int idx = tid + p * 256;
            int r = idx & 31, rest = idx >> 5;
            int nt = rest % 10, sl = rest / 10;
            int sidx = (dbase >> 3) + sl;
            __hip_bfloat16 tmp[8];
            #pragma unroll
            for (int q = 0; q < 8; ++q)
                tmp[q] = __float2bfloat16(ld[sl * 8 + q][nt * 32 + r]);
            dT[(nt * 32 + sidx) * 32 + r] = *(bf16x8*)tmp;
        }
    }
    {
        bf16x8* dB = (bf16x8*)vbf2 + (size_t)j * 10240;
        int dt = dbase >> 5;
        #pragma unroll
        for (int p = 0; p < 5; ++p) {
            int idx = tid + p * 256;
            int r = idx & 31, ks = idx >> 5;    // 0..39
            __hip_bfloat16 tmp[8];
            #pragma unroll
            for (int q = 0; q < 8; ++q)
                tmp[q] = __float2bfloat16(ld[r][ks * 8 + q]);
            dB[(dt * 40 + ks) * 32 + r] = *(bf16x8*)tmp;
        }
    }
}

// ---- one block (256 thr) per (i,j) pair; Smat[j*64+i] = S[i][j]
// Round-11 coalesced-fragment structure + IN-REGISTER softmaxes:
// GEMM1 accs never round-trip through LDS. softmax-n = 5x shfl_xor over
// r-lanes + 24x4 cross-wave LDS table; softmax-t = in-thread 12 exps +
// shfl_xor(32). Only alpha (GEMM2 A operand) is stored to LDS.
// Register ledger: 48 acc + fm/fiv 24 + frag/addr ~30 = ~105 unified < 128
// -> launch_bounds(256,4) (cap 128) is the only safe point; watch WRITE_SIZE.
__global__ __launch_bounds__(256, 4) void pair_kernel(const __hip_bfloat16* __restrict__ eTf,
                                                      const __hip_bfloat16* __restrict__ vTf,
                                                      const __hip_bfloat16* __restrict__ vbf2,
                                                      const float* __restrict__ eE,
                                                      float* __restrict__ Smat) {
    __shared__ __align__(16) __hip_bfloat16 alpha[32 * 320];   // 20480 B, XOR-swizzled rows
    __shared__ __align__(16) float pm[24][4];                  // per-wave row max
    __shared__ __align__(16) float ps[24][4];                  // per-wave row sum

    const int tid = threadIdx.x;
    const int wave = tid >> 6, lane = tid & 63;
    const int r = lane & 31, g2 = lane >> 5;
    // XCD swizzle (T1): bijective (4096 = 8*512)
    const int bid = (blockIdx.x & 7) * 512 + (blockIdx.x >> 3);
    const int i = bid & 63, j = bid >> 6;

    char* ab = (char*)alpha;

    // pad-lite zeroing: rows 24..31 and swizzled cols 304..319 of all rows.
    {
        uint32_t* rz = (uint32_t*)(ab + 24 * 640);   // 8 rows * 640 B
        #pragma unroll
        for (int q = 0; q < 5; ++q) rz[tid + q * 256] = 0u;
        int t = tid >> 3, n0 = 304 + 2 * (tid & 7);
        int boff = (t * 640 + 2 * n0) ^ ((t & 7) << 4);
        *(uint32_t*)(ab + boff) = 0u;
    }

    // ========== GEMM1: s[t][n], 32x32 tiles, accs stay in registers ============
    const bf16x8* eF = (const bf16x8*)eTf + (size_t)i * 1024;
    const bf16x8* vF = (const bf16x8*)vTf + (size_t)j * 10240;
    f32x16 acc[3];
    #pragma unroll
    for (int ti = 0; ti < 3; ++ti) {
        #pragma unroll
        for (int z = 0; z < 16; ++z) acc[ti][z] = 0.f;
        int nt2 = wave + ti * 4;               // 10 n-tiles over 4 waves
        if (nt2 < 10) {                        // wave-uniform
            #pragma unroll
            for (int s = 0; s < 16; ++s) {
                bf16x8 af = eF[(s * 2 + g2) * 32 + r];
                bf16x8 bf = vF[(nt2 * 32 + s * 2 + g2) * 32 + r];
                acc[ti] = __builtin_amdgcn_mfma_f32_32x32x16_bf16(af, bf, acc[ti], 0, 0, 0);
            }
        }
    }

    // ========== softmax over n: in-register, shfl over r-lanes + wave table =====
    // lane's column n = nt2*32 + r is valid iff nt2<9 || r==0 (NR=289).
    float fm[12], fiv[12];
    #pragma unroll
    for (int reg = 0; reg < 12; ++reg) {
        float m = -INFINITY;
        #pragma unroll
        for (int ti = 0; ti < 3; ++ti) {
            int nt2 = wave + ti * 4;
            bool okn = (nt2 < 9) | ((nt2 == 9) & (r == 0));
            m = okn ? fmaxf(m, acc[ti][reg]) : m;
        }
        #pragma unroll
        for (int mk = 1; mk <= 16; mk <<= 1) m = fmaxf(m, __shfl_xor(m, mk, 64));
        float su = 0.f;
        #pragma unroll
        for (int ti = 0; ti < 3; ++ti) {
            int nt2 = wave + ti * 4;
            bool okn = (nt2 < 9) | ((nt2 == 9) & (r == 0));
            su += okn ? __expf(acc[ti][reg] - m) : 0.f;
        }
        #pragma unroll
        for (int mk = 1; mk <= 16; mk <<= 1) su += __shfl_xor(su, mk, 64);
        if (r == 0) {                          // lane 0 (g2=0) and lane 32 (g2=1)
            int t = (reg & 3) + 8 * (reg >> 2) + 4 * g2;
            pm[t][wave] = m; ps[t][wave] = su;
        }
    }
    __syncthreads();
    #pragma unroll
    for (int reg = 0; reg < 12; ++reg) {
        int t = (reg & 3) + 8 * (reg >> 2) + 4 * g2;
        f32x4 p4 = *(const f32x4*)&pm[t][0];
        f32x4 q4 = *(const f32x4*)&ps[t][0];
        float m = fmaxf(fmaxf(p4[0], p4[1]), fmaxf(p4[2], p4[3]));
        float su = q4[0] * __expf(p4[0] - m) + q4[1] * __expf(p4[1] - m)
                 + q4[2] * __expf(p4[2] - m) + q4[3] * __expf(p4[3] - m);
        fm[reg] = m; fiv[reg] = 1.f / su;
    }

    // ========== softmax over t: in-register (12 in-thread + xor-32) ============
    // arg = 4*s_norm in (0,4] -> no max subtraction needed.
    #pragma unroll
    for (int ti = 0; ti < 3; ++ti) {
        int nt2 = wave + ti * 4;
        if (nt2 < 10) {                        // wave-uniform
            float ex[12];
            float colsum = 0.f;
            #pragma unroll
            for (int reg = 0; reg < 12; ++reg) {
                float p = __expf(acc[ti][reg] - fm[reg]) * fiv[reg];   // s_norm
                float e4 = __expf(4.f * p);
                ex[reg] = e4; colsum += e4;
            }
            colsum += __shfl_xor(colsum, 32, 64);   // other g2 half: 24-term total
            float inv = 1.f / colsum;
            int n = nt2 * 32 + r;
            if (nt2 < 9 || r < 16) {           // n<304 (cols 289..303 garbage-finite, B=0)
                #pragma unroll
                for (int reg = 0; reg < 12; ++reg) {
                    int t = (reg & 3) + 8 * (reg >> 2) + 4 * g2;
                    int boff = (t * 640 + 2 * n) ^ ((t & 7) << 4);
                    *(__hip_bfloat16*)(ab + boff) = __float2bfloat16(ex[reg] * inv);
                }
            }
        }
    }
    __syncthreads();

    // ====== GEMM2: c[t][d] = sum_n alpha[t][n]*v[d][n], 32x32 tiles =============
    const bf16x8* vB2f = (const bf16x8*)vbf2 + (size_t)j * 10240;
    const float* eEp = eE + (size_t)i * 6144;

    float ssum = 0.f;
    #pragma unroll
    for (int ti2 = 0; ti2 < 2; ++ti2) {
        int dt = wave + ti2 * 4;               // 8 d-tiles over 4 waves
        f32x16 a2;
        #pragma unroll
        for (int z = 0; z < 16; ++z) a2[z] = 0.f;
        int sw = (r & 7) << 4;
        #pragma unroll
        for (int ks = 0; ks < 20; ++ks) {
            bf16x8 af = *(const bf16x8*)(ab + ((r * 640 + ks * 32 + g2 * 16) ^ sw));
            bf16x8 bf = vB2f[(dt * 40 + ks * 2 + g2) * 32 + r];
            a2 = __builtin_amdgcn_mfma_f32_32x32x16_bf16(af, bf, a2, 0, 0, 0);
        }
        // epilogue: cosine over t for this lane's d column
        float dot = 0.f, cn2 = 0.f, en2 = 0.f;
        #pragma unroll
        for (int reg = 0; reg < 12; ++reg) {
            float ev = eEp[((dt * 2 + g2) * 12 + reg) * 32 + r];
            dot = fmaf(a2[reg], ev, dot);
            cn2 = fmaf(a2[reg], a2[reg], cn2);
            en2 = fmaf(ev, ev, en2);
        }
        dot += __shfl_xor(dot, 32, 64);
        cn2 += __shfl_xor(cn2, 32, 64);
        en2 += __shfl_xor(en2, 32, 64);
        float R = dot / fmaxf(sqrtf(cn2) * sqrtf(en2), 1e-8f);
        ssum += __expf(5.f * R);               // 5R in [-5,5]: plain sum is safe
    }
    // butterfly-sum over the wave (each d counted twice: lanes l and l^32)
    #pragma unroll
    for (int mk = 1; mk <= 32; mk <<= 1) ssum += __shfl_xor(ssum, mk, 64);
    __syncthreads();                           // all waves done reading alpha/pm
    float* red = (float*)pm;
    if (lane == 0) red[wave] = ssum;
    __syncthreads();
    if (tid == 0) {
        float total = red[0] + red[1] + red[2] + red[3];
        float lse = logf(total * 0.5f);        // /2 removes the lane-pair duplication
        Smat[bid] = powf(lse, 0.2f);
    }
}

// out[0..63] = sum_j S[i][j]; out[64..127] = sum_i S[i][j]
__global__ void reduce_kernel(const float* __restrict__ Smat, float* __restrict__ out) {
    int k = threadIdx.x;   // 0..127
    float s = 0.f;
    if (k < 64) {
        int i = k;
        for (int j = 0; j < BB; ++j) s += Smat[j * 64 + i];
        out[i] = s;
    } else {
        int jq = k - 64;
        for (int i = 0; i < BB; ++i) s += Smat[jq * 64 + i];
        out[64 + jq] = s;
    }
}

extern "C" void kernel_launch(void* const* d_in, const int* in_sizes, int n_in,
                              void* d_out, int out_size, void* d_ws, size_t ws_size,
                              hipStream_t stream) {
    const float* e = (const float*)d_in[0];
    const float* v = (const float*)d_in[1];
    float* out = (float*)d_out;
    char* ws = (char*)d_ws;
    __hip_bfloat16* eTf  = (__hip_bfloat16*)(ws + ETF_OFF);
    __hip_bfloat16* vTf  = (__hip_bfloat16*)(ws + VTF_OFF);
    __hip_bfloat16* vbf2 = (__hip_bfloat16*)(ws + VB2_OFF);
    float* eE  = (float*)(ws + EE_OFF);
    float* Smat = (float*)(ws + SMAT_OFF);

    conv_e_kernel<<<64, 256, 0, stream>>>(e, eTf, eE);
    conv_v_kernel<<<512, 256, 0, stream>>>(v, vTf, vbf2);
    pair_kernel<<<BB * BB, 256, 0, stream>>>(eTf, vTf, vbf2, eE, Smat);
    reduce_kernel<<<1, 128, 0, stream>>>(Smat, out);
}

// Round 13
// 127.396 us; speedup vs baseline: 1.1170x; 1.1170x over previous
//
#include <hip/hip_runtime.h>
#include <hip/hip_bf16.h>
#include <math.h>

#define BB 64
#define DD 256
#define TT 24
#define NR 289

typedef float f32x4  __attribute__((ext_vector_type(4)));
typedef float f32x16 __attribute__((ext_vector_type(16)));
typedef short bf16x8 __attribute__((ext_vector_type(8)));

// ws layout (bytes) — ALL operands fragment-major (lane-minor, 16B/lane):
#define ETF_OFF  0ul                     // eTf  [64][32 sidx][32 r] bf16x8     1,048,576
#define VTF_OFF  1048576ul               // vTf  [64][10 nt][32 sidx][32 r]    10,485,760
#define VB2_OFF  11534336ul              // vbf2 [64][8 dt][40 ks][32 r]       10,485,760
#define EE_OFF   22020096ul              // eE   [64][8 dt][2 g2][12 reg][32 r] f32 1,572,864
#define SMAT_OFF 23592960ul              // Smat [4096] f32

// ---- e -> eTf fragments (GEMM1 A) + eE f32 fragments (epilogue)
__global__ void conv_e_kernel(const float* __restrict__ e,
                              __hip_bfloat16* __restrict__ eTf,
                              float* __restrict__ eE) {
    int i = blockIdx.x, tid = threadIdx.x;
    const float* ei = e + (size_t)i * DD * TT;
    bf16x8* dst = (bf16x8*)eTf + (size_t)i * 1024;
    #pragma unroll
    for (int p = 0; p < 4; ++p) {
        int idx = tid + p * 256;
        int r = idx & 31, sidx = idx >> 5;
        int d0 = sidx * 8;
        __hip_bfloat16 tmp[8];
        #pragma unroll
        for (int q = 0; q < 8; ++q) {
            float f = (r < TT) ? ei[(d0 + q) * TT + r] : 0.f;
            tmp[q] = __float2bfloat16(f);
        }
        dst[idx] = *(bf16x8*)tmp;
    }
    float* dstE = eE + (size_t)i * 6144;
    #pragma unroll
    for (int p = 0; p < 24; ++p) {
        int idx = tid + p * 256;
        int r = idx & 31, rest = idx >> 5;
        int reg = rest % 12, gdt = rest / 12;
        int g2 = gdt & 1, dt = gdt >> 1;
        int t = (reg & 3) + 8 * (reg >> 2) + 4 * g2;
        dstE[idx] = ei[(dt * 32 + r) * TT + t];
    }
}

// ---- v -> vTf (GEMM1 B, transposed) + vbf2 (GEMM2 B), both fragment-major
__global__ __launch_bounds__(256) void conv_v_kernel(const float* __restrict__ v,
                                                     __hip_bfloat16* __restrict__ vTf,
                                                     __hip_bfloat16* __restrict__ vbf2) {
    __shared__ float ld[32][321];
    int j = blockIdx.x >> 3;
    int dbase = (blockIdx.x & 7) * 32;
    int tid = threadIdx.x;
    const float* vj = v + (size_t)j * DD * NR;
    for (int r = 0; r < 32; ++r) {
        const float* row = vj + (size_t)(dbase + r) * NR;
        ld[r][tid] = row[tid];
        if (tid < 64) {
            int n = 256 + tid;
            ld[r][n] = (n < NR) ? row[n] : 0.f;
        }
    }
    __syncthreads();
    {
        bf16x8* dT = (bf16x8*)vTf + (size_t)j * 10240;
        #pragma unroll
        for (int p = 0; p < 5; ++p) {
            int idx = tid + p * 256;
            int r = idx & 31, rest = idx >> 5;
            int nt = rest % 10, sl = rest / 10;
            int sidx = (dbase >> 3) + sl;
            __hip_bfloat16 tmp[8];
            #pragma unroll
            for (int q = 0; q < 8; ++q)
                tmp[q] = __float2bfloat16(ld[sl * 8 + q][nt * 32 + r]);
            dT[(nt * 32 + sidx) * 32 + r] = *(bf16x8*)tmp;
        }
    }
    {
        bf16x8* dB = (bf16x8*)vbf2 + (size_t)j * 10240;
        int dt = dbase >> 5;
        #pragma unroll
        for (int p = 0; p < 5; ++p) {
            int idx = tid + p * 256;
            int r = idx & 31, ks = idx >> 5;    // 0..39
            __hip_bfloat16 tmp[8];
            #pragma unroll
            for (int q = 0; q < 8; ++q)
                tmp[q] = __float2bfloat16(ld[r][ks * 8 + q]);
            dB[(dt * 40 + ks) * 32 + r] = *(bf16x8*)tmp;
        }
    }
}

// ---- one block (256 thr) per (i,j) pair; Smat[j*64+i] = S[i][j]
// Round-12 in-register-softmax design, register-trimmed to fit cap 128:
//  * fused L[reg] = rowmax + log(rowsum)  (kills fiv[12])
//  * e4 written back into acc in place    (kills ex[12])
// Ledger: acc 48 + L 12 + frags/addr ~35 = ~95-110 unified < 128.
__global__ __launch_bounds__(256, 4) void pair_kernel(const __hip_bfloat16* __restrict__ eTf,
                                                      const __hip_bfloat16* __restrict__ vTf,
                                                      const __hip_bfloat16* __restrict__ vbf2,
                                                      const float* __restrict__ eE,
                                                      float* __restrict__ Smat) {
    __shared__ __align__(16) __hip_bfloat16 alpha[32 * 320];   // 20480 B, XOR-swizzled rows
    __shared__ __align__(16) float pm[24][4];                  // per-wave row max
    __shared__ __align__(16) float ps[24][4];                  // per-wave row sum

    const int tid = threadIdx.x;
    const int wave = tid >> 6, lane = tid & 63;
    const int r = lane & 31, g2 = lane >> 5;
    // XCD swizzle (T1): bijective (4096 = 8*512)
    const int bid = (blockIdx.x & 7) * 512 + (blockIdx.x >> 3);
    const int i = bid & 63, j = bid >> 6;

    char* ab = (char*)alpha;

    // pad-lite zeroing: rows 24..31 and swizzled cols 304..319 of all rows.
    {
        uint32_t* rz = (uint32_t*)(ab + 24 * 640);   // 8 rows * 640 B
        #pragma unroll
        for (int q = 0; q < 5; ++q) rz[tid + q * 256] = 0u;
        int t = tid >> 3, n0 = 304 + 2 * (tid & 7);
        int boff = (t * 640 + 2 * n0) ^ ((t & 7) << 4);
        *(uint32_t*)(ab + boff) = 0u;
    }

    // ========== GEMM1: s[t][n], 32x32 tiles, accs stay in registers ============
    const bf16x8* eF = (const bf16x8*)eTf + (size_t)i * 1024;
    const bf16x8* vF = (const bf16x8*)vTf + (size_t)j * 10240;
    f32x16 acc[3];
    #pragma unroll
    for (int ti = 0; ti < 3; ++ti) {
        #pragma unroll
        for (int z = 0; z < 16; ++z) acc[ti][z] = 0.f;
        int nt2 = wave + ti * 4;               // 10 n-tiles over 4 waves
        if (nt2 < 10) {                        // wave-uniform
            #pragma unroll
            for (int s = 0; s < 16; ++s) {
                bf16x8 af = eF[(s * 2 + g2) * 32 + r];
                bf16x8 bf = vF[(nt2 * 32 + s * 2 + g2) * 32 + r];
                acc[ti] = __builtin_amdgcn_mfma_f32_32x32x16_bf16(af, bf, acc[ti], 0, 0, 0);
            }
        }
    }

    // ========== softmax over n: in-register, shfl over r-lanes + wave table =====
    // lane's column n = nt2*32 + r is valid iff nt2<9 || r==0 (NR=289).
    #pragma unroll
    for (int reg = 0; reg < 12; ++reg) {
        float m = -INFINITY;
        #pragma unroll
        for (int ti = 0; ti < 3; ++ti) {
            int nt2 = wave + ti * 4;
            bool okn = (nt2 < 9) | ((nt2 == 9) & (r == 0));
            m = okn ? fmaxf(m, acc[ti][reg]) : m;
        }
        #pragma unroll
        for (int mk = 1; mk <= 16; mk <<= 1) m = fmaxf(m, __shfl_xor(m, mk, 64));
        float su = 0.f;
        #pragma unroll
        for (int ti = 0; ti < 3; ++ti) {
            int nt2 = wave + ti * 4;
            bool okn = (nt2 < 9) | ((nt2 == 9) & (r == 0));
            su += okn ? __expf(acc[ti][reg] - m) : 0.f;
        }
        #pragma unroll
        for (int mk = 1; mk <= 16; mk <<= 1) su += __shfl_xor(su, mk, 64);
        if (r == 0) {                          // lane 0 (g2=0) and lane 32 (g2=1)
            int t = (reg & 3) + 8 * (reg >> 2) + 4 * g2;
            pm[t][wave] = m; ps[t][wave] = su;
        }
    }
    __syncthreads();
    // combine 4 per-wave partials -> single log-norm constant per row
    float L[12];
    #pragma unroll
    for (int reg = 0; reg < 12; ++reg) {
        int t = (reg & 3) + 8 * (reg >> 2) + 4 * g2;
        f32x4 p4 = *(const f32x4*)&pm[t][0];
        f32x4 q4 = *(const f32x4*)&ps[t][0];
        float m = fmaxf(fmaxf(p4[0], p4[1]), fmaxf(p4[2], p4[3]));
        float su = q4[0] * __expf(p4[0] - m) + q4[1] * __expf(p4[1] - m)
                 + q4[2] * __expf(p4[2] - m) + q4[3] * __expf(p4[3] - m);
        L[reg] = m + __logf(su);               // s_norm = exp(acc - L)
    }

    // ========== softmax over t: in-register, e4 written back into acc ==========
    // arg = 4*s_norm in (0,4] -> no max subtraction needed.
    #pragma unroll
    for (int ti = 0; ti < 3; ++ti) {
        int nt2 = wave + ti * 4;
        if (nt2 < 10) {                        // wave-uniform
            float colsum = 0.f;
            #pragma unroll
            for (int reg = 0; reg < 12; ++reg) {
                float p = __expf(acc[ti][reg] - L[reg]);   // s_norm
                float e4 = __expf(4.f * p);
                acc[ti][reg] = e4; colsum += e4;
            }
            colsum += __shfl_xor(colsum, 32, 64);   // other g2 half: 24-term total
            float inv = 1.f / colsum;
            int n = nt2 * 32 + r;
            if (nt2 < 9 || r < 16) {           // n<304 (cols 289..303 garbage-finite, B=0)
                #pragma unroll
                for (int reg = 0; reg < 12; ++reg) {
                    int t = (reg & 3) + 8 * (reg >> 2) + 4 * g2;
                    int boff = (t * 640 + 2 * n) ^ ((t & 7) << 4);
                    *(__hip_bfloat16*)(ab + boff) = __float2bfloat16(acc[ti][reg] * inv);
                }
            }
        }
    }
    __syncthreads();

    // ====== GEMM2: c[t][d] = sum_n alpha[t][n]*v[d][n], 32x32 tiles =============
    const bf16x8* vB2f = (const bf16x8*)vbf2 + (size_t)j * 10240;
    const float* eEp = eE + (size_t)i * 6144;

    float ssum = 0.f;
    #pragma unroll
    for (int ti2 = 0; ti2 < 2; ++ti2) {
        int dt = wave + ti2 * 4;               // 8 d-tiles over 4 waves
        f32x16 a2;
        #pragma unroll
        for (int z = 0; z < 16; ++z) a2[z] = 0.f;
        int sw = (r & 7) << 4;
        #pragma unroll
        for (int ks = 0; ks < 20; ++ks) {
            bf16x8 af = *(const bf16x8*)(ab + ((r * 640 + ks * 32 + g2 * 16) ^ sw));
            bf16x8 bf = vB2f[(dt * 40 + ks * 2 + g2) * 32 + r];
            a2 = __builtin_amdgcn_mfma_f32_32x32x16_bf16(af, bf, a2, 0, 0, 0);
        }
        // epilogue: cosine over t for this lane's d column
        float dot = 0.f, cn2 = 0.f, en2 = 0.f;
        #pragma unroll
        for (int reg = 0; reg < 12; ++reg) {
            float ev = eEp[((dt * 2 + g2) * 12 + reg) * 32 + r];
            dot = fmaf(a2[reg], ev, dot);
            cn2 = fmaf(a2[reg], a2[reg], cn2);
            en2 = fmaf(ev, ev, en2);
        }
        dot += __shfl_xor(dot, 32, 64);
        cn2 += __shfl_xor(cn2, 32, 64);
        en2 += __shfl_xor(en2, 32, 64);
        float R = dot / fmaxf(sqrtf(cn2) * sqrtf(en2), 1e-8f);
        ssum += __expf(5.f * R);               // 5R in [-5,5]: plain sum is safe
    }
    // butterfly-sum over the wave (each d counted twice: lanes l and l^32)
    #pragma unroll
    for (int mk = 1; mk <= 32; mk <<= 1) ssum += __shfl_xor(ssum, mk, 64);
    __syncthreads();                           // all waves done reading alpha/pm
    float* red = (float*)pm;
    if (lane == 0) red[wave] = ssum;
    __syncthreads();
    if (tid == 0) {
        float total = red[0] + red[1] + red[2] + red[3];
        float lse = logf(total * 0.5f);        // /2 removes the lane-pair duplication
        Smat[bid] = powf(lse, 0.2f);
    }
}

// out[0..63] = sum_j S[i][j]; out[64..127] = sum_i S[i][j]
__global__ void reduce_kernel(const float* __restrict__ Smat, float* __restrict__ out) {
    int k = threadIdx.x;   // 0..127
    float s = 0.f;
    if (k < 64) {
        int i = k;
        for (int j = 0; j < BB; ++j) s += Smat[j * 64 + i];
        out[i] = s;
    } else {
        int jq = k - 64;
        for (int i = 0; i < BB; ++i) s += Smat[jq * 64 + i];
        out[64 + jq] = s;
    }
}

extern "C" void kernel_launch(void* const* d_in, const int* in_sizes, int n_in,
                              void* d_out, int out_size, void* d_ws, size_t ws_size,
                              hipStream_t stream) {
    const float* e = (const float*)d_in[0];
    const float* v = (const float*)d_in[1];
    float* out = (float*)d_out;
    char* ws = (char*)d_ws;
    __hip_bfloat16* eTf  = (__hip_bfloat16*)(ws + ETF_OFF);
    __hip_bfloat16* vTf  = (__hip_bfloat16*)(ws + VTF_OFF);
    __hip_bfloat16* vbf2 = (__hip_bfloat16*)(ws + VB2_OFF);
    float* eE  = (float*)(ws + EE_OFF);
    float* Smat = (float*)(ws + SMAT_OFF);

    conv_e_kernel<<<64, 256, 0, stream>>>(e, eTf, eE);
    conv_v_kernel<<<512, 256, 0, stream>>>(v, vTf, vbf2);
    pair_kernel<<<BB * BB, 256, 0, stream>>>(eTf, vTf, vbf2, eE, Smat);
    reduce_kernel<<<1, 128, 0, stream>>>(Smat, out);
}